// Round 13
// baseline (195.703 us; speedup 1.0000x reference)
//
#include <hip/hip_runtime.h>
#include <hip/hip_fp16.h>

#define D 128
#define NEG_SLOPE 0.2f
#define BKT_SHIFT 7     // 128 nodes per bucket
#define NBKP 392        // padded bucket-count stride

typedef __attribute__((ext_vector_type(8))) _Float16 v8h;
typedef __attribute__((ext_vector_type(4))) float v4f;

// ---------------- prep: W^T fragment-order swizzle + wa = W@a --------------
// Swizzled layout (fp16): idx = t*2048 + ks*512 + quad*128 + nn*8 + j
//   holds W[k][n] with n = t*16+nn, k = ks*32 + quad*8 + j.
__global__ __launch_bounds__(256) void prep_kernel(
    const float* __restrict__ W1, const float* __restrict__ W2,
    const float* __restrict__ as1, const float* __restrict__ ad1,
    const float* __restrict__ as2, const float* __restrict__ ad2,
    __half* __restrict__ sw1, __half* __restrict__ sw2,
    __half* __restrict__ wa1, __half* __restrict__ wa2) {
  const float* W = blockIdx.y ? W2 : W1;
  if (blockIdx.x < 64) {
    __half* sw = blockIdx.y ? sw2 : sw1;
    int idx = blockIdx.x * 256 + threadIdx.x;
    int j = idx & 7, nn = (idx >> 3) & 15, quad = (idx >> 7) & 3;
    int ks = (idx >> 9) & 3, t = idx >> 11;
    int n = t * 16 + nn;
    int k = ks * 32 + quad * 8 + j;
    sw[idx] = __float2half(W[(size_t)k * D + n]);
  } else {
    // wa[r][k] = sum_n W[k][n] * a_r[n]
    int tid = threadIdx.x;
    int k = tid & 127;
    const float* vec = (tid < 128) ? (blockIdx.y ? as2 : as1)
                                   : (blockIdx.y ? ad2 : ad1);
    float s = 0.f;
    #pragma unroll 8
    for (int n = 0; n < 128; n += 4) {
      float4 wv = *(const float4*)&W[(size_t)k * D + n];
      float4 av = *(const float4*)&vec[n];
      s += wv.x * av.x + wv.y * av.y + wv.z * av.z + wv.w * av.w;
    }
    __half* wa = blockIdx.y ? wa2 : wa1;
    wa[(tid >> 7) * 128 + k] = __float2half(s);
  }
}

// ---------------- bucketed CSR build (no global atomics) -------------------

__global__ __launch_bounds__(256) void tot_kernel(const int* __restrict__ cnt_g,
                                                  int* __restrict__ tot, int nbe) {
  __shared__ int s[256];
  int bkt = blockIdx.x, t = threadIdx.x;
  s[t] = (t < nbe) ? cnt_g[t * NBKP + bkt] : 0;
  __syncthreads();
  #pragma unroll
  for (int o = 128; o; o >>= 1) { if (t < o) s[t] += s[t + o]; __syncthreads(); }
  if (t == 0) tot[bkt] = s[0];
}

__global__ __launch_bounds__(512) void base_kernel(
    const int* __restrict__ cnt_g, const int* __restrict__ tot,
    int* __restrict__ bktBase, int* __restrict__ off,
    int* __restrict__ base_g, int nbe, int nbk, int N, int EP) {
  __shared__ int sb[512], s[512];
  int bkt = blockIdx.x, t = threadIdx.x;
  int tv = (t < nbk) ? tot[t] : 0;
  sb[t] = tv;
  __syncthreads();
  for (int o = 1; o < 512; o <<= 1) {
    int u = (t >= o) ? sb[t - o] : 0;
    __syncthreads();
    sb[t] += u;
    __syncthreads();
  }
  int myBase = (bkt == 0) ? 0 : sb[bkt - 1];
  if (blockIdx.x == 0) {
    if (t < nbk) bktBase[t] = (t == 0) ? 0 : sb[t - 1];
    if (t == 0) { bktBase[nbk] = EP; off[N] = EP; }
  }
  int v = (t < nbe) ? cnt_g[t * NBKP + bkt] : 0;
  s[t] = v;
  __syncthreads();
  for (int o = 1; o < 512; o <<= 1) {
    int u = (t >= o) ? s[t - o] : 0;
    __syncthreads();
    s[t] += u;
    __syncthreads();
  }
  if (t < nbe) base_g[t * NBKP + bkt] = myBase + (s[t] - v);
}

__global__ __launch_bounds__(256) void bucket_scatter(
    const int* __restrict__ srcE, const int* __restrict__ dstE, int E, int N,
    const int* __restrict__ base_g, int* __restrict__ pk,
    int nbk, int nbe) {
  __shared__ int cur[512];
  int eid = blockIdx.x;
  for (int t = threadIdx.x; t < nbk; t += 256) cur[t] = base_g[eid * NBKP + t];
  __syncthreads();
  int EP = E + N;
  int C = (EP + nbe - 1) / nbe;
  int st = eid * C, en = min(EP, st + C);
  for (int i = st + (int)threadIdx.x; i < en; i += 256) {
    int s, d;
    if (i < E) { s = srcE[i]; d = dstE[i]; } else { s = i - E; d = s; }
    int pos = atomicAdd(&cur[d >> BKT_SHIFT], 1);
    pk[pos] = (s << BKT_SHIFT) | (d & 127);
  }
}

__global__ __launch_bounds__(256) void bucket_csr(
    const int* __restrict__ pk,
    const int* __restrict__ bktBase, int* __restrict__ off, int* __restrict__ csr, int N) {
  __shared__ int cnt[128], cur[128], tmp[128];
  int bkt = blockIdx.x, t = threadIdx.x;
  int node0 = bkt << BKT_SHIFT;
  int nn = min(128, N - node0);
  if (t < 128) cnt[t] = 0;
  __syncthreads();
  int st = bktBase[bkt], en = bktBase[bkt + 1];
  for (int e = st + t; e < en; e += 256) atomicAdd(&cnt[pk[e] & 127], 1);
  __syncthreads();
  if (t < 128) tmp[t] = cnt[t];
  __syncthreads();
  for (int o = 1; o < 128; o <<= 1) {
    int u = (t < 128 && t >= o) ? tmp[t - o] : 0;
    __syncthreads();
    if (t < 128) tmp[t] += u;
    __syncthreads();
  }
  if (t < 128) {
    int excl = tmp[t] - cnt[t];
    cur[t] = excl;
    if (t < nn) off[node0 + t] = st + excl;
  }
  __syncthreads();
  for (int e = st + t; e < en; e += 256) {
    int v = pk[e];
    int r = atomicAdd(&cur[v & 127], 1);
    csr[st + r] = v >> BKT_SHIFT;
  }
}

// ---------------- MFMA GEMM(+scores) || bucket edge-count ------------------
// R23: 512-thread blocks, 128 rows each. Halves the per-block W-staging
// events (782 -> 391) at IDENTICAL total wave count (391x8 = 782x4), so TLP
// is preserved (R16's failure mode avoided). X-loads hoisted (R22).
__global__ __launch_bounds__(512, 4) void gemm_ec_fused(
    const float* __restrict__ Xf, const __half* __restrict__ Xh,
    const __half* __restrict__ WtSw, const __half* __restrict__ waG,
    __half* __restrict__ H, float* __restrict__ Ss, float* __restrict__ Sd, int N,
    const int* __restrict__ dstE, int E, int* __restrict__ cnt_g,
    int nbk, int nbGemm, int nbEdge)
{
  __shared__ _Float16 WtS[16384];   // fragment-order W^T (32 KB)
  __shared__ _Float16 waS[256];     // [2][128]
  __shared__ int cntS[512];

  int tid = threadIdx.x;
  int bid = blockIdx.x;
  // generalized role split (nbGemm != nbEdge ok)
  int role, rid;
  if (nbEdge > 0) {
    int k2 = 2 * (nbGemm < nbEdge ? nbGemm : nbEdge);
    if (bid < k2)              { role = bid & 1; rid = bid >> 1; }
    else if (nbGemm >= nbEdge) { role = 0; rid = bid - nbEdge; }
    else                       { role = 1; rid = bid - nbGemm; }
  } else { role = 0; rid = bid; }

  if (role) {
    // ---- edge-count role (512 threads) ----
    int eid = rid;
    for (int t = tid; t < nbk; t += 512) cntS[t] = 0;
    __syncthreads();
    int EP = E + N;
    int C = (EP + nbEdge - 1) / nbEdge;
    int st = eid * C, en = min(EP, st + C);
    for (int i = st + tid; i < en; i += 512) {
      int d = (i < E) ? dstE[i] : (i - E);
      atomicAdd(&cntS[d >> BKT_SHIFT], 1);
    }
    __syncthreads();
    for (int t = tid; t < nbk; t += 512) cnt_g[(size_t)eid * NBKP + t] = cntS[t];
    return;
  }
  int gemmId = rid;

  int wid = tid >> 6, lane = tid & 63;      // wid 0..7
  int quad = lane >> 4, nn = lane & 15;
  int row = gemmId * 128 + wid * 16 + nn;
  int rowc = min(row, N - 1);

  // ---- issue X b-fragment loads FIRST (hide under staging) ----
  v8h b[4];
  if (Xh) {
    #pragma unroll
    for (int ks = 0; ks < 4; ++ks)
      b[ks] = *(const v8h*)&Xh[(size_t)rowc * D + ks * 32 + quad * 8];
  } else {
    #pragma unroll
    for (int ks = 0; ks < 4; ++ks) {
      int k0 = ks * 32 + quad * 8;
      float4 x0 = *(const float4*)&Xf[(size_t)rowc * D + k0];
      float4 x1 = *(const float4*)&Xf[(size_t)rowc * D + k0 + 4];
      v8h t;
      t[0] = (_Float16)x0.x; t[1] = (_Float16)x0.y;
      t[2] = (_Float16)x0.z; t[3] = (_Float16)x0.w;
      t[4] = (_Float16)x1.x; t[5] = (_Float16)x1.y;
      t[6] = (_Float16)x1.z; t[7] = (_Float16)x1.w;
      b[ks] = t;
    }
  }

  // stage swizzled W^T + wa: pure linear copies, bank-minimal (512 thr: 4 it)
  #pragma unroll
  for (int it = 0; it < 4; ++it) {
    int lin = it * 512 + tid;
    *(v8h*)&WtS[lin * 8] = *(const v8h*)&WtSw[lin * 8];
  }
  if (tid < 32) *(v8h*)&waS[tid * 8] = *(const v8h*)&waG[tid * 8];
  __syncthreads();

  v4f acc[9];
  #pragma unroll
  for (int t = 0; t < 9; ++t) acc[t] = (v4f){0.f, 0.f, 0.f, 0.f};

  #pragma unroll
  for (int ks = 0; ks < 4; ++ks) {
    int k0 = ks * 32 + quad * 8;
    #pragma unroll
    for (int t = 0; t < 8; ++t) {
      v8h a = *(const v8h*)&WtS[t * 2048 + ks * 512 + quad * 128 + nn * 8];
      acc[t] = __builtin_amdgcn_mfma_f32_16x16x32_f16(a, b[ks], acc[t], 0, 0, 0);
    }
    v8h awv = *(const v8h*)&waS[(nn & 1) * 128 + k0];
    acc[8] = __builtin_amdgcn_mfma_f32_16x16x32_f16(awv, b[ks], acc[8], 0, 0, 0);
  }

  if (row < N) {
    #pragma unroll
    for (int t = 0; t < 8; ++t) {
      __half2 h0 = __floats2half2_rn(acc[t].x, acc[t].y);
      __half2 h1 = __floats2half2_rn(acc[t].z, acc[t].w);
      *(__half2*)&H[(size_t)row * D + t * 16 + quad * 4]     = h0;
      *(__half2*)&H[(size_t)row * D + t * 16 + quad * 4 + 2] = h1;
    }
    if (quad == 0) { Ss[row] = acc[8].x; Sd[row] = acc[8].y; }
  }
}

// ============ R20: 4-nodes-per-wave agg core (group = 16 lanes) ============
// Group g of each wave owns node n = node0 + wid*4 + g. Edges in 16-wide
// per-group chunks; 2-deep gather MLP (16 rows in flight per wave across
// groups). Out-of-range lanes hold p=0 (no masking needed).

// ---------------- fused agg(layer1) + gemm(layer2) + scores(layer2) --------
__global__ __launch_bounds__(256) void aggemm_kernel(
    const __half* __restrict__ H, const float* __restrict__ Ssrc, const float* __restrict__ Sdst,
    const int* __restrict__ off, const int* __restrict__ csr, const float* __restrict__ bias,
    const __half* __restrict__ W2sw, const __half* __restrict__ wa2G,
    __half* __restrict__ H2, float* __restrict__ Ss2, float* __restrict__ Sd2, int N)
{
  __shared__ _Float16 tile[16][136];

  int tid = threadIdx.x;
  int wid = tid >> 6, lane = tid & 63;
  int g = lane >> 4, l16 = lane & 15;
  int c8 = l16 * 8;
  int node0 = blockIdx.x * 16;
  int r = wid * 4 + g;
  int n = node0 + r;
  int nc = min(n, N - 1);

  int st = off[nc], en = off[nc + 1];
  if (n >= N) en = st;               // inactive group
  float sd = Sdst[nc];

  float z = 0.f;
  float acc[8];
  #pragma unroll
  for (int u = 0; u < 8; ++u) acc[u] = 0.f;

  int lb = g << 4;
  for (int base = st; __any(base < en); base += 16) {
    int idx = base + l16;
    float p = 0.f; int s = 0;
    if (idx < en) {
      s = csr[idx];
      float e = Ssrc[s] + sd;
      e = e > 0.f ? e : NEG_SLOPE * e;
      p = __expf(fminf(e, 80.f));
    }
    z += p;
    int c = en - base;
    c = c < 0 ? 0 : (c > 16 ? 16 : c);
    int cm = max(c, __shfl_xor(c, 16));
    cm = max(cm, __shfl_xor(cm, 32));
    for (int i = 0; i < cm; i += 2) {
      float p0 = __shfl(p, lb + i);
      int   s0 = __shfl(s, lb + i);
      float p1 = __shfl(p, lb + i + 1);
      int   s1 = __shfl(s, lb + i + 1);
      v8h h0 = *(const v8h*)&H[(size_t)s0 * D + c8];
      v8h h1 = *(const v8h*)&H[(size_t)s1 * D + c8];
      #pragma unroll
      for (int u = 0; u < 8; ++u) acc[u] += p0 * (float)h0[u];
      #pragma unroll
      for (int u = 0; u < 8; ++u) acc[u] += p1 * (float)h1[u];
    }
  }
  // z-reduction within the 16-lane group
  z += __shfl_xor(z, 8);
  z += __shfl_xor(z, 4);
  z += __shfl_xor(z, 2);
  z += __shfl_xor(z, 1);

  if (n < N) {
    float inv = 1.f / (z + 1e-16f);
    float4 b0 = *(const float4*)&bias[c8];
    float4 b1 = *(const float4*)&bias[c8 + 4];
    v8h ov;
    ov[0] = (_Float16)fmaxf(acc[0] * inv + b0.x, 0.f);
    ov[1] = (_Float16)fmaxf(acc[1] * inv + b0.y, 0.f);
    ov[2] = (_Float16)fmaxf(acc[2] * inv + b0.z, 0.f);
    ov[3] = (_Float16)fmaxf(acc[3] * inv + b0.w, 0.f);
    ov[4] = (_Float16)fmaxf(acc[4] * inv + b1.x, 0.f);
    ov[5] = (_Float16)fmaxf(acc[5] * inv + b1.y, 0.f);
    ov[6] = (_Float16)fmaxf(acc[6] * inv + b1.z, 0.f);
    ov[7] = (_Float16)fmaxf(acc[7] * inv + b1.w, 0.f);
    *(v8h*)&tile[r][c8] = ov;
  }
  __syncthreads();

  // ---- layer-2 GEMM on the 16-row tile (R18-proven fragment pattern) ----
  int quad = g, nn = l16;
  int row = node0 + nn;
  bool wr = row < N;

  v8h b[4];
  #pragma unroll
  for (int ks = 0; ks < 4; ++ks)
    b[ks] = *(const v8h*)&tile[nn][ks * 32 + quad * 8];

  #pragma unroll
  for (int t2 = 0; t2 < 2; ++t2) {
    int t = wid * 2 + t2;
    v4f acg = (v4f){0.f, 0.f, 0.f, 0.f};
    #pragma unroll
    for (int ks = 0; ks < 4; ++ks) {
      v8h a = *(const v8h*)&W2sw[t * 2048 + ks * 512 + quad * 128 + nn * 8];
      acg = __builtin_amdgcn_mfma_f32_16x16x32_f16(a, b[ks], acg, 0, 0, 0);
    }
    if (wr) {
      __half2 h0 = __floats2half2_rn(acg.x, acg.y);
      __half2 h1 = __floats2half2_rn(acg.z, acg.w);
      *(__half2*)&H2[(size_t)row * D + t * 16 + quad * 4]     = h0;
      *(__half2*)&H2[(size_t)row * D + t * 16 + quad * 4 + 2] = h1;
    }
  }
  if (wid == 0) {
    v4f acc8 = (v4f){0.f, 0.f, 0.f, 0.f};
    #pragma unroll
    for (int ks = 0; ks < 4; ++ks) {
      v8h awv = *(const v8h*)&wa2G[(nn & 1) * 128 + ks * 32 + quad * 8];
      acc8 = __builtin_amdgcn_mfma_f32_16x16x32_f16(awv, b[ks], acc8, 0, 0, 0);
    }
    if (wr && quad == 0) { Ss2[row] = acc8.x; Sd2[row] = acc8.y; }
  }
}

// ---------------- layer-2 aggregate -> output (4 nodes/wave) ---------------
__global__ __launch_bounds__(256) void agg_kernel(
    const __half* __restrict__ H, const float* __restrict__ Ssrc, const float* __restrict__ Sdst,
    const int* __restrict__ off, const int* __restrict__ csr, const float* __restrict__ bias,
    float* __restrict__ outF, int N)
{
  int tid = threadIdx.x;
  int wid = tid >> 6, lane = tid & 63;
  int g = lane >> 4, l16 = lane & 15;
  int c8 = l16 * 8;
  int n = blockIdx.x * 16 + wid * 4 + g;
  int nc = min(n, N - 1);

  int st = off[nc], en = off[nc + 1];
  if (n >= N) en = st;
  float sd = Sdst[nc];

  float z = 0.f;
  float acc[8];
  #pragma unroll
  for (int u = 0; u < 8; ++u) acc[u] = 0.f;

  int lb = g << 4;
  for (int base = st; __any(base < en); base += 16) {
    int idx = base + l16;
    float p = 0.f; int s = 0;
    if (idx < en) {
      s = csr[idx];
      float e = Ssrc[s] + sd;
      e = e > 0.f ? e : NEG_SLOPE * e;
      p = __expf(fminf(e, 80.f));
    }
    z += p;
    int c = en - base;
    c = c < 0 ? 0 : (c > 16 ? 16 : c);
    int cm = max(c, __shfl_xor(c, 16));
    cm = max(cm, __shfl_xor(cm, 32));
    for (int i = 0; i < cm; i += 2) {
      float p0 = __shfl(p, lb + i);
      int   s0 = __shfl(s, lb + i);
      float p1 = __shfl(p, lb + i + 1);
      int   s1 = __shfl(s, lb + i + 1);
      v8h h0 = *(const v8h*)&H[(size_t)s0 * D + c8];
      v8h h1 = *(const v8h*)&H[(size_t)s1 * D + c8];
      #pragma unroll
      for (int u = 0; u < 8; ++u) acc[u] += p0 * (float)h0[u];
      #pragma unroll
      for (int u = 0; u < 8; ++u) acc[u] += p1 * (float)h1[u];
    }
  }
  z += __shfl_xor(z, 8);
  z += __shfl_xor(z, 4);
  z += __shfl_xor(z, 2);
  z += __shfl_xor(z, 1);

  if (n < N) {
    float inv = 1.f / (z + 1e-16f);
    float4 b0 = *(const float4*)&bias[c8];
    float4 b1 = *(const float4*)&bias[c8 + 4];
    float o0 = acc[0] * inv + b0.x, o1 = acc[1] * inv + b0.y;
    float o2 = acc[2] * inv + b0.z, o3 = acc[3] * inv + b0.w;
    float o4 = acc[4] * inv + b1.x, o5 = acc[5] * inv + b1.y;
    float o6 = acc[6] * inv + b1.z, o7 = acc[7] * inv + b1.w;
    *(float4*)&outF[(size_t)n * D + c8]     = make_float4(o0, o1, o2, o3);
    *(float4*)&outF[(size_t)n * D + c8 + 4] = make_float4(o4, o5, o6, o7);
  }
}

// ---------------- launcher ----------------

extern "C" void kernel_launch(void* const* d_in, const int* in_sizes, int n_in,
                              void* d_out, int out_size, void* d_ws, size_t ws_size,
                              hipStream_t stream) {
  const float* x   = (const float*)d_in[0];
  const int*   ei  = (const int*)d_in[1];
  const float* W1  = (const float*)d_in[2];
  const float* as1 = (const float*)d_in[3];
  const float* ad1 = (const float*)d_in[4];
  const float* b1  = (const float*)d_in[5];
  const float* W2  = (const float*)d_in[6];
  const float* as2 = (const float*)d_in[7];
  const float* ad2 = (const float*)d_in[8];
  const float* b2  = (const float*)d_in[9];

  int N  = in_sizes[0] / D;
  int E  = in_sizes[1] / 2;
  int EP = E + N;
  const int* src = ei;
  const int* dst = ei + E;

  int nbk = (N + 127) >> BKT_SHIFT;    // 391 buckets
  int nbe = 256;                       // edge-count blocks
  int nbGemm = (N + 127) / 128;        // 391 (512-thread blocks, 128 rows)

  char* w = (char*)d_ws;
  auto alloc = [&](size_t bytes) -> char* {
    char* p = w; w += (bytes + 511) & ~(size_t)511; return p;
  };
  __half*   sw1    = (__half*)alloc((size_t)D * D * 2);
  __half*   sw2    = (__half*)alloc((size_t)D * D * 2);
  __half*   wa1    = (__half*)alloc((size_t)2 * D * 2);
  __half*   wa2    = (__half*)alloc((size_t)2 * D * 2);
  int*      cnt_g  = (int*)alloc((size_t)nbe * NBKP * 4);
  int*      base_g = (int*)alloc((size_t)nbe * NBKP * 4);
  int*      tot    = (int*)alloc((size_t)NBKP * 4);
  int*      bktB   = (int*)alloc((size_t)(NBKP + 1) * 4);
  int*      off    = (int*)alloc(((size_t)N + 1) * 4);
  int*      csr    = (int*)alloc((size_t)EP * 4);
  int*      pk     = (int*)alloc((size_t)EP * 4);
  float*    ssrc   = (float*)alloc((size_t)N * 4);
  float*    sdst   = (float*)alloc((size_t)N * 4);
  float*    ss2    = (float*)alloc((size_t)N * 4);
  float*    sd2    = (float*)alloc((size_t)N * 4);
  __half*   h      = (__half*)alloc((size_t)N * D * 2);
  __half*   h2     = (__half*)alloc((size_t)N * D * 2);

  // swizzled W^T + wa for both layers
  prep_kernel<<<dim3(65, 2), 256, 0, stream>>>(W1, W2, as1, ad1, as2, ad2,
                                               sw1, sw2, wa1, wa2);

  // layer-1 GEMM (512-thr blocks, 128 rows) interleaved with edge-count
  gemm_ec_fused<<<nbGemm + nbe, 512, 0, stream>>>(
      x, nullptr, sw1, wa1, h, ssrc, sdst, N,
      dst, E, cnt_g, nbk, nbGemm, nbe);

  // CSR build (no global atomics)
  tot_kernel<<<nbk, 256, 0, stream>>>(cnt_g, tot, nbe);
  base_kernel<<<nbk, 512, 0, stream>>>(cnt_g, tot, bktB, off, base_g,
                                       nbe, nbk, N, EP);
  bucket_scatter<<<nbe, 256, 0, stream>>>(src, dst, E, N, base_g, pk, nbk, nbe);
  bucket_csr<<<nbk, 256, 0, stream>>>(pk, bktB, off, csr, N);

  // FUSED: layer-1 aggregate (4 nodes/wave) + layer-2 GEMM + layer-2 scores
  aggemm_kernel<<<(N + 15) / 16, 256, 0, stream>>>(
      h, ssrc, sdst, off, csr, b1, sw2, wa2, h2, ss2, sd2, N);

  // layer-2 aggregate (4 nodes/wave) -> output
  agg_kernel<<<(N + 15) / 16, 256, 0, stream>>>(h2, ss2, sd2, off, csr, b2,
                                                (float*)d_out, N);
}

// Round 14
// 190.679 us; speedup vs baseline: 1.0263x; 1.0263x over previous
//
#include <hip/hip_runtime.h>
#include <hip/hip_fp16.h>

#define D 128
#define NEG_SLOPE 0.2f
#define BKT_SHIFT 7     // 128 nodes per bucket
#define NBKP 392        // padded bucket-count stride

typedef __attribute__((ext_vector_type(8))) _Float16 v8h;
typedef __attribute__((ext_vector_type(4))) float v4f;

// ---------------- prep: W^T fragment-order swizzle + wa = W@a --------------
// Swizzled layout (fp16): idx = t*2048 + ks*512 + quad*128 + nn*8 + j
//   holds W[k][n] with n = t*16+nn, k = ks*32 + quad*8 + j.
__global__ __launch_bounds__(256) void prep_kernel(
    const float* __restrict__ W1, const float* __restrict__ W2,
    const float* __restrict__ as1, const float* __restrict__ ad1,
    const float* __restrict__ as2, const float* __restrict__ ad2,
    __half* __restrict__ sw1, __half* __restrict__ sw2,
    __half* __restrict__ wa1, __half* __restrict__ wa2) {
  const float* W = blockIdx.y ? W2 : W1;
  if (blockIdx.x < 64) {
    __half* sw = blockIdx.y ? sw2 : sw1;
    int idx = blockIdx.x * 256 + threadIdx.x;
    int j = idx & 7, nn = (idx >> 3) & 15, quad = (idx >> 7) & 3;
    int ks = (idx >> 9) & 3, t = idx >> 11;
    int n = t * 16 + nn;
    int k = ks * 32 + quad * 8 + j;
    sw[idx] = __float2half(W[(size_t)k * D + n]);
  } else {
    // wa[r][k] = sum_n W[k][n] * a_r[n]
    int tid = threadIdx.x;
    int k = tid & 127;
    const float* vec = (tid < 128) ? (blockIdx.y ? as2 : as1)
                                   : (blockIdx.y ? ad2 : ad1);
    float s = 0.f;
    #pragma unroll 8
    for (int n = 0; n < 128; n += 4) {
      float4 wv = *(const float4*)&W[(size_t)k * D + n];
      float4 av = *(const float4*)&vec[n];
      s += wv.x * av.x + wv.y * av.y + wv.z * av.z + wv.w * av.w;
    }
    __half* wa = blockIdx.y ? wa2 : wa1;
    wa[(tid >> 7) * 128 + k] = __float2half(s);
  }
}

// ---------------- bucketed CSR build (no global atomics) -------------------

__global__ __launch_bounds__(256) void tot_kernel(const int* __restrict__ cnt_g,
                                                  int* __restrict__ tot, int nbe) {
  __shared__ int s[256];
  int bkt = blockIdx.x, t = threadIdx.x;
  s[t] = (t < nbe) ? cnt_g[t * NBKP + bkt] : 0;
  __syncthreads();
  #pragma unroll
  for (int o = 128; o; o >>= 1) { if (t < o) s[t] += s[t + o]; __syncthreads(); }
  if (t == 0) tot[bkt] = s[0];
}

__global__ __launch_bounds__(512) void base_kernel(
    const int* __restrict__ cnt_g, const int* __restrict__ tot,
    int* __restrict__ bktBase, int* __restrict__ off,
    int* __restrict__ base_g, int nbe, int nbk, int N, int EP) {
  __shared__ int sb[512], s[512];
  int bkt = blockIdx.x, t = threadIdx.x;
  int tv = (t < nbk) ? tot[t] : 0;
  sb[t] = tv;
  __syncthreads();
  for (int o = 1; o < 512; o <<= 1) {
    int u = (t >= o) ? sb[t - o] : 0;
    __syncthreads();
    sb[t] += u;
    __syncthreads();
  }
  int myBase = (bkt == 0) ? 0 : sb[bkt - 1];
  if (blockIdx.x == 0) {
    if (t < nbk) bktBase[t] = (t == 0) ? 0 : sb[t - 1];
    if (t == 0) { bktBase[nbk] = EP; off[N] = EP; }
  }
  int v = (t < nbe) ? cnt_g[t * NBKP + bkt] : 0;
  s[t] = v;
  __syncthreads();
  for (int o = 1; o < 512; o <<= 1) {
    int u = (t >= o) ? s[t - o] : 0;
    __syncthreads();
    s[t] += u;
    __syncthreads();
  }
  if (t < nbe) base_g[t * NBKP + bkt] = myBase + (s[t] - v);
}

// R24: 512 threads (2x waves/SIMD for latency hiding on the random pk
// scatter); identical data layout, loop strides 512.
__global__ __launch_bounds__(512) void bucket_scatter(
    const int* __restrict__ srcE, const int* __restrict__ dstE, int E, int N,
    const int* __restrict__ base_g, int* __restrict__ pk,
    int nbk, int nbe) {
  __shared__ int cur[512];
  int eid = blockIdx.x;
  for (int t = threadIdx.x; t < nbk; t += 512) cur[t] = base_g[eid * NBKP + t];
  __syncthreads();
  int EP = E + N;
  int C = (EP + nbe - 1) / nbe;
  int st = eid * C, en = min(EP, st + C);
  for (int i = st + (int)threadIdx.x; i < en; i += 512) {
    int s, d;
    if (i < E) { s = srcE[i]; d = dstE[i]; } else { s = i - E; d = s; }
    int pos = atomicAdd(&cur[d >> BKT_SHIFT], 1);
    pk[pos] = (s << BKT_SHIFT) | (d & 127);
  }
}

// R24: 512 threads (same rationale; histogram/scatter strides 512, scans
// keep t<128 guards).
__global__ __launch_bounds__(512) void bucket_csr(
    const int* __restrict__ pk,
    const int* __restrict__ bktBase, int* __restrict__ off, int* __restrict__ csr, int N) {
  __shared__ int cnt[128], cur[128], tmp[128];
  int bkt = blockIdx.x, t = threadIdx.x;
  int node0 = bkt << BKT_SHIFT;
  int nn = min(128, N - node0);
  if (t < 128) cnt[t] = 0;
  __syncthreads();
  int st = bktBase[bkt], en = bktBase[bkt + 1];
  for (int e = st + t; e < en; e += 512) atomicAdd(&cnt[pk[e] & 127], 1);
  __syncthreads();
  if (t < 128) tmp[t] = cnt[t];
  __syncthreads();
  for (int o = 1; o < 128; o <<= 1) {
    int u = (t < 128 && t >= o) ? tmp[t - o] : 0;
    __syncthreads();
    if (t < 128) tmp[t] += u;
    __syncthreads();
  }
  if (t < 128) {
    int excl = tmp[t] - cnt[t];
    cur[t] = excl;
    if (t < nn) off[node0 + t] = st + excl;
  }
  __syncthreads();
  for (int e = st + t; e < en; e += 512) {
    int v = pk[e];
    int r = atomicAdd(&cur[v & 127], 1);
    csr[st + r] = v >> BKT_SHIFT;
  }
}

// ---------------- MFMA GEMM(+scores) || bucket edge-count ------------------
// R22 form (best): 256-thr blocks, 64 rows, X-loads hoisted above staging.
__global__ __launch_bounds__(256, 4) void gemm_ec_fused(
    const float* __restrict__ Xf, const __half* __restrict__ Xh,
    const __half* __restrict__ WtSw, const __half* __restrict__ waG,
    __half* __restrict__ H, float* __restrict__ Ss, float* __restrict__ Sd, int N,
    const int* __restrict__ dstE, int E, int* __restrict__ cnt_g,
    int nbk, int nbGemm, int nbEdge)
{
  __shared__ _Float16 WtS[16384];   // fragment-order W^T (32 KB)
  __shared__ _Float16 waS[256];     // [2][128]
  __shared__ int cntS[512];

  int tid = threadIdx.x;
  int gemmId;
  if (nbEdge > 0 && (int)blockIdx.x < 2 * nbEdge) {
    if (blockIdx.x & 1) {
      // ---- edge-count role ----
      int eid = blockIdx.x >> 1;
      for (int t = tid; t < nbk; t += 256) cntS[t] = 0;
      __syncthreads();
      int EP = E + N;
      int C = (EP + nbEdge - 1) / nbEdge;
      int st = eid * C, en = min(EP, st + C);
      for (int i = st + tid; i < en; i += 256) {
        int d = (i < E) ? dstE[i] : (i - E);
        atomicAdd(&cntS[d >> BKT_SHIFT], 1);
      }
      __syncthreads();
      for (int t = tid; t < nbk; t += 256) cnt_g[eid * NBKP + t] = cntS[t];
      return;
    }
    gemmId = blockIdx.x >> 1;
  } else {
    gemmId = (nbEdge > 0) ? ((int)blockIdx.x - nbEdge) : (int)blockIdx.x;
  }

  int wid = tid >> 6, lane = tid & 63;
  int quad = lane >> 4, nn = lane & 15;
  int row = gemmId * 64 + wid * 16 + nn;
  int rowc = min(row, N - 1);

  // ---- issue X b-fragment loads FIRST (hide under staging) ----
  v8h b[4];
  if (Xh) {
    #pragma unroll
    for (int ks = 0; ks < 4; ++ks)
      b[ks] = *(const v8h*)&Xh[(size_t)rowc * D + ks * 32 + quad * 8];
  } else {
    #pragma unroll
    for (int ks = 0; ks < 4; ++ks) {
      int k0 = ks * 32 + quad * 8;
      float4 x0 = *(const float4*)&Xf[(size_t)rowc * D + k0];
      float4 x1 = *(const float4*)&Xf[(size_t)rowc * D + k0 + 4];
      v8h t;
      t[0] = (_Float16)x0.x; t[1] = (_Float16)x0.y;
      t[2] = (_Float16)x0.z; t[3] = (_Float16)x0.w;
      t[4] = (_Float16)x1.x; t[5] = (_Float16)x1.y;
      t[6] = (_Float16)x1.z; t[7] = (_Float16)x1.w;
      b[ks] = t;
    }
  }

  // stage swizzled W^T + wa: pure linear copies, bank-minimal
  #pragma unroll
  for (int it = 0; it < 8; ++it) {
    int lin = it * 256 + tid;
    *(v8h*)&WtS[lin * 8] = *(const v8h*)&WtSw[lin * 8];
  }
  if (tid < 32) *(v8h*)&waS[tid * 8] = *(const v8h*)&waG[tid * 8];
  __syncthreads();

  v4f acc[9];
  #pragma unroll
  for (int t = 0; t < 9; ++t) acc[t] = (v4f){0.f, 0.f, 0.f, 0.f};

  #pragma unroll
  for (int ks = 0; ks < 4; ++ks) {
    int k0 = ks * 32 + quad * 8;
    #pragma unroll
    for (int t = 0; t < 8; ++t) {
      v8h a = *(const v8h*)&WtS[t * 2048 + ks * 512 + quad * 128 + nn * 8];
      acc[t] = __builtin_amdgcn_mfma_f32_16x16x32_f16(a, b[ks], acc[t], 0, 0, 0);
    }
    v8h awv = *(const v8h*)&waS[(nn & 1) * 128 + k0];
    acc[8] = __builtin_amdgcn_mfma_f32_16x16x32_f16(awv, b[ks], acc[8], 0, 0, 0);
  }

  if (row < N) {
    #pragma unroll
    for (int t = 0; t < 8; ++t) {
      __half2 h0 = __floats2half2_rn(acc[t].x, acc[t].y);
      __half2 h1 = __floats2half2_rn(acc[t].z, acc[t].w);
      *(__half2*)&H[(size_t)row * D + t * 16 + quad * 4]     = h0;
      *(__half2*)&H[(size_t)row * D + t * 16 + quad * 4 + 2] = h1;
    }
    if (quad == 0) { Ss[row] = acc[8].x; Sd[row] = acc[8].y; }
  }
}

// ============ R20: 4-nodes-per-wave agg core (group = 16 lanes) ============
// Group g of each wave owns node n = node0 + wid*4 + g. Edges in 16-wide
// per-group chunks; 2-deep gather MLP (16 rows in flight per wave across
// groups). Out-of-range lanes hold p=0 (no masking needed).

// ---------------- fused agg(layer1) + gemm(layer2) + scores(layer2) --------
__global__ __launch_bounds__(256) void aggemm_kernel(
    const __half* __restrict__ H, const float* __restrict__ Ssrc, const float* __restrict__ Sdst,
    const int* __restrict__ off, const int* __restrict__ csr, const float* __restrict__ bias,
    const __half* __restrict__ W2sw, const __half* __restrict__ wa2G,
    __half* __restrict__ H2, float* __restrict__ Ss2, float* __restrict__ Sd2, int N)
{
  __shared__ _Float16 tile[16][136];

  int tid = threadIdx.x;
  int wid = tid >> 6, lane = tid & 63;
  int g = lane >> 4, l16 = lane & 15;
  int c8 = l16 * 8;
  int node0 = blockIdx.x * 16;
  int r = wid * 4 + g;
  int n = node0 + r;
  int nc = min(n, N - 1);

  int st = off[nc], en = off[nc + 1];
  if (n >= N) en = st;               // inactive group
  float sd = Sdst[nc];

  float z = 0.f;
  float acc[8];
  #pragma unroll
  for (int u = 0; u < 8; ++u) acc[u] = 0.f;

  int lb = g << 4;
  for (int base = st; __any(base < en); base += 16) {
    int idx = base + l16;
    float p = 0.f; int s = 0;
    if (idx < en) {
      s = csr[idx];
      float e = Ssrc[s] + sd;
      e = e > 0.f ? e : NEG_SLOPE * e;
      p = __expf(fminf(e, 80.f));
    }
    z += p;
    int c = en - base;
    c = c < 0 ? 0 : (c > 16 ? 16 : c);
    int cm = max(c, __shfl_xor(c, 16));
    cm = max(cm, __shfl_xor(cm, 32));
    for (int i = 0; i < cm; i += 2) {
      float p0 = __shfl(p, lb + i);
      int   s0 = __shfl(s, lb + i);
      float p1 = __shfl(p, lb + i + 1);
      int   s1 = __shfl(s, lb + i + 1);
      v8h h0 = *(const v8h*)&H[(size_t)s0 * D + c8];
      v8h h1 = *(const v8h*)&H[(size_t)s1 * D + c8];
      #pragma unroll
      for (int u = 0; u < 8; ++u) acc[u] += p0 * (float)h0[u];
      #pragma unroll
      for (int u = 0; u < 8; ++u) acc[u] += p1 * (float)h1[u];
    }
  }
  // z-reduction within the 16-lane group
  z += __shfl_xor(z, 8);
  z += __shfl_xor(z, 4);
  z += __shfl_xor(z, 2);
  z += __shfl_xor(z, 1);

  if (n < N) {
    float inv = 1.f / (z + 1e-16f);
    float4 b0 = *(const float4*)&bias[c8];
    float4 b1 = *(const float4*)&bias[c8 + 4];
    v8h ov;
    ov[0] = (_Float16)fmaxf(acc[0] * inv + b0.x, 0.f);
    ov[1] = (_Float16)fmaxf(acc[1] * inv + b0.y, 0.f);
    ov[2] = (_Float16)fmaxf(acc[2] * inv + b0.z, 0.f);
    ov[3] = (_Float16)fmaxf(acc[3] * inv + b0.w, 0.f);
    ov[4] = (_Float16)fmaxf(acc[4] * inv + b1.x, 0.f);
    ov[5] = (_Float16)fmaxf(acc[5] * inv + b1.y, 0.f);
    ov[6] = (_Float16)fmaxf(acc[6] * inv + b1.z, 0.f);
    ov[7] = (_Float16)fmaxf(acc[7] * inv + b1.w, 0.f);
    *(v8h*)&tile[r][c8] = ov;
  }
  __syncthreads();

  // ---- layer-2 GEMM on the 16-row tile (R18-proven fragment pattern) ----
  int quad = g, nn = l16;
  int row = node0 + nn;
  bool wr = row < N;

  v8h b[4];
  #pragma unroll
  for (int ks = 0; ks < 4; ++ks)
    b[ks] = *(const v8h*)&tile[nn][ks * 32 + quad * 8];

  #pragma unroll
  for (int t2 = 0; t2 < 2; ++t2) {
    int t = wid * 2 + t2;
    v4f acg = (v4f){0.f, 0.f, 0.f, 0.f};
    #pragma unroll
    for (int ks = 0; ks < 4; ++ks) {
      v8h a = *(const v8h*)&W2sw[t * 2048 + ks * 512 + quad * 128 + nn * 8];
      acg = __builtin_amdgcn_mfma_f32_16x16x32_f16(a, b[ks], acg, 0, 0, 0);
    }
    if (wr) {
      __half2 h0 = __floats2half2_rn(acg.x, acg.y);
      __half2 h1 = __floats2half2_rn(acg.z, acg.w);
      *(__half2*)&H2[(size_t)row * D + t * 16 + quad * 4]     = h0;
      *(__half2*)&H2[(size_t)row * D + t * 16 + quad * 4 + 2] = h1;
    }
  }
  if (wid == 0) {
    v4f acc8 = (v4f){0.f, 0.f, 0.f, 0.f};
    #pragma unroll
    for (int ks = 0; ks < 4; ++ks) {
      v8h awv = *(const v8h*)&wa2G[(nn & 1) * 128 + ks * 32 + quad * 8];
      acc8 = __builtin_amdgcn_mfma_f32_16x16x32_f16(awv, b[ks], acc8, 0, 0, 0);
    }
    if (wr && quad == 0) { Ss2[row] = acc8.x; Sd2[row] = acc8.y; }
  }
}

// ---------------- layer-2 aggregate -> output (4 nodes/wave) ---------------
__global__ __launch_bounds__(256) void agg_kernel(
    const __half* __restrict__ H, const float* __restrict__ Ssrc, const float* __restrict__ Sdst,
    const int* __restrict__ off, const int* __restrict__ csr, const float* __restrict__ bias,
    float* __restrict__ outF, int N)
{
  int tid = threadIdx.x;
  int wid = tid >> 6, lane = tid & 63;
  int g = lane >> 4, l16 = lane & 15;
  int c8 = l16 * 8;
  int n = blockIdx.x * 16 + wid * 4 + g;
  int nc = min(n, N - 1);

  int st = off[nc], en = off[nc + 1];
  if (n >= N) en = st;
  float sd = Sdst[nc];

  float z = 0.f;
  float acc[8];
  #pragma unroll
  for (int u = 0; u < 8; ++u) acc[u] = 0.f;

  int lb = g << 4;
  for (int base = st; __any(base < en); base += 16) {
    int idx = base + l16;
    float p = 0.f; int s = 0;
    if (idx < en) {
      s = csr[idx];
      float e = Ssrc[s] + sd;
      e = e > 0.f ? e : NEG_SLOPE * e;
      p = __expf(fminf(e, 80.f));
    }
    z += p;
    int c = en - base;
    c = c < 0 ? 0 : (c > 16 ? 16 : c);
    int cm = max(c, __shfl_xor(c, 16));
    cm = max(cm, __shfl_xor(cm, 32));
    for (int i = 0; i < cm; i += 2) {
      float p0 = __shfl(p, lb + i);
      int   s0 = __shfl(s, lb + i);
      float p1 = __shfl(p, lb + i + 1);
      int   s1 = __shfl(s, lb + i + 1);
      v8h h0 = *(const v8h*)&H[(size_t)s0 * D + c8];
      v8h h1 = *(const v8h*)&H[(size_t)s1 * D + c8];
      #pragma unroll
      for (int u = 0; u < 8; ++u) acc[u] += p0 * (float)h0[u];
      #pragma unroll
      for (int u = 0; u < 8; ++u) acc[u] += p1 * (float)h1[u];
    }
  }
  z += __shfl_xor(z, 8);
  z += __shfl_xor(z, 4);
  z += __shfl_xor(z, 2);
  z += __shfl_xor(z, 1);

  if (n < N) {
    float inv = 1.f / (z + 1e-16f);
    float4 b0 = *(const float4*)&bias[c8];
    float4 b1 = *(const float4*)&bias[c8 + 4];
    float o0 = acc[0] * inv + b0.x, o1 = acc[1] * inv + b0.y;
    float o2 = acc[2] * inv + b0.z, o3 = acc[3] * inv + b0.w;
    float o4 = acc[4] * inv + b1.x, o5 = acc[5] * inv + b1.y;
    float o6 = acc[6] * inv + b1.z, o7 = acc[7] * inv + b1.w;
    *(float4*)&outF[(size_t)n * D + c8]     = make_float4(o0, o1, o2, o3);
    *(float4*)&outF[(size_t)n * D + c8 + 4] = make_float4(o4, o5, o6, o7);
  }
}

// ---------------- launcher ----------------

extern "C" void kernel_launch(void* const* d_in, const int* in_sizes, int n_in,
                              void* d_out, int out_size, void* d_ws, size_t ws_size,
                              hipStream_t stream) {
  const float* x   = (const float*)d_in[0];
  const int*   ei  = (const int*)d_in[1];
  const float* W1  = (const float*)d_in[2];
  const float* as1 = (const float*)d_in[3];
  const float* ad1 = (const float*)d_in[4];
  const float* b1  = (const float*)d_in[5];
  const float* W2  = (const float*)d_in[6];
  const float* as2 = (const float*)d_in[7];
  const float* ad2 = (const float*)d_in[8];
  const float* b2  = (const float*)d_in[9];

  int N  = in_sizes[0] / D;
  int E  = in_sizes[1] / 2;
  int EP = E + N;
  const int* src = ei;
  const int* dst = ei + E;

  int nbk = (N + 127) >> BKT_SHIFT;   // 391 buckets
  int nbe = 256;                      // edge-count blocks
  int nbGemm = (N + 63) / 64;         // 782

  char* w = (char*)d_ws;
  auto alloc = [&](size_t bytes) -> char* {
    char* p = w; w += (bytes + 511) & ~(size_t)511; return p;
  };
  __half*   sw1    = (__half*)alloc((size_t)D * D * 2);
  __half*   sw2    = (__half*)alloc((size_t)D * D * 2);
  __half*   wa1    = (__half*)alloc((size_t)2 * D * 2);
  __half*   wa2    = (__half*)alloc((size_t)2 * D * 2);
  int*      cnt_g  = (int*)alloc((size_t)nbe * NBKP * 4);
  int*      base_g = (int*)alloc((size_t)nbe * NBKP * 4);
  int*      tot    = (int*)alloc((size_t)NBKP * 4);
  int*      bktB   = (int*)alloc((size_t)(NBKP + 1) * 4);
  int*      off    = (int*)alloc(((size_t)N + 1) * 4);
  int*      csr    = (int*)alloc((size_t)EP * 4);
  int*      pk     = (int*)alloc((size_t)EP * 4);
  float*    ssrc   = (float*)alloc((size_t)N * 4);
  float*    sdst   = (float*)alloc((size_t)N * 4);
  float*    ss2    = (float*)alloc((size_t)N * 4);
  float*    sd2    = (float*)alloc((size_t)N * 4);
  __half*   h      = (__half*)alloc((size_t)N * D * 2);
  __half*   h2     = (__half*)alloc((size_t)N * D * 2);

  // swizzled W^T + wa for both layers
  prep_kernel<<<dim3(65, 2), 256, 0, stream>>>(W1, W2, as1, ad1, as2, ad2,
                                               sw1, sw2, wa1, wa2);

  // layer-1 GEMM (MFMA, X-loads hoisted) interleaved with bucket edge-count
  gemm_ec_fused<<<nbGemm + nbe, 256, 0, stream>>>(
      x, nullptr, sw1, wa1, h, ssrc, sdst, N,
      dst, E, cnt_g, nbk, nbGemm, nbe);

  // CSR build (no global atomics; scatter/csr at 512 threads for TLP)
  tot_kernel<<<nbk, 256, 0, stream>>>(cnt_g, tot, nbe);
  base_kernel<<<nbk, 512, 0, stream>>>(cnt_g, tot, bktB, off, base_g,
                                       nbe, nbk, N, EP);
  bucket_scatter<<<nbe, 512, 0, stream>>>(src, dst, E, N, base_g, pk, nbk, nbe);
  bucket_csr<<<nbk, 512, 0, stream>>>(pk, bktB, off, csr, N);

  // FUSED: layer-1 aggregate (4 nodes/wave) + layer-2 GEMM + layer-2 scores
  aggemm_kernel<<<(N + 15) / 16, 256, 0, stream>>>(
      h, ssrc, sdst, off, csr, b1, sw2, wa2, h2, ss2, sd2, N);

  // layer-2 aggregate (4 nodes/wave) -> output
  agg_kernel<<<(N + 15) / 16, 256, 0, stream>>>(h2, ss2, sd2, off, csr, b2,
                                                (float*)d_out, N);
}